// Round 5
// baseline (748.817 us; speedup 1.0000x reference)
//
#include <hip/hip_runtime.h>
#include <cstddef>

// Problem constants
#define NN 512
#define DD 128
#define HH 4
#define LL 4
#define GHD 32
#define OUTD 128
#define NBLK 512

// ws layout (float offsets). EM region sized 4*N*D for compat; only N*D used,
// so the barrier words live at ws + N*D (guaranteed-allocated, untouched).
static constexpr size_t OFF_EM  = 0;                                   // [N][D]
static constexpr size_t OFF_BAR = (size_t)NN * DD;                     // 2 uints
static constexpr size_t OFF_ANF = (size_t)4 * NN * DD;                 // [H][N][D]
static constexpr size_t OFF_DEN = OFF_ANF + (size_t)HH * NN * DD;      // [H][N]
static constexpr size_t OFF_EO  = OFF_DEN + (size_t)HH * NN;           // [H][L][N][GHD]
static constexpr size_t OFF_G   = OFF_EO  + (size_t)HH * LL * NN * GHD;
static constexpr size_t OFF_AG  = OFF_G   + (size_t)HH * LL * NN * GHD;

__device__ __forceinline__ void f4acc(float4& a, const float4& v) {
    a.x += v.x; a.y += v.y; a.z += v.z; a.w += v.w;
}

// Sense-reversing device barrier: self-resetting counter + generation word.
// All threads fence (agent scope) on both sides; t0 arrives/spins.
__device__ __forceinline__ void gbar(unsigned* cnt, unsigned* gen) {
    __threadfence();
    __syncthreads();
    if (threadIdx.x == 0) {
        unsigned g = __hip_atomic_load(gen, __ATOMIC_RELAXED, __HIP_MEMORY_SCOPE_AGENT);
        if (atomicAdd(cnt, 1u) == (unsigned)(NBLK - 1)) {
            __hip_atomic_store(cnt, 0u, __ATOMIC_RELAXED, __HIP_MEMORY_SCOPE_AGENT);
            __hip_atomic_store(gen, g + 1u, __ATOMIC_RELEASE, __HIP_MEMORY_SCOPE_AGENT);
        } else {
            while (__hip_atomic_load(gen, __ATOMIC_RELAXED, __HIP_MEMORY_SCOPE_AGENT) == g)
                __builtin_amdgcn_s_sleep(1);
        }
    }
    __syncthreads();
    __threadfence();
}

// ===========================================================================
// Single persistent kernel: 512 blocks x 256 threads, 2 blocks/CU.
// A: edge_mean (deep-MLP stream)  B: Anf+deg  | bar | C: EO+g0 | bar |
// D/E/F: layers 1..3 (bar each)  | bar | G: final linear.
// ===========================================================================
__global__ __launch_bounds__(256, 2) void fused_kernel(
    const float* __restrict__ node_feat,
    const float* __restrict__ edge_feat,
    const float* __restrict__ adj,
    const float* __restrict__ W_edge,
    const float* __restrict__ Wn0,
    const float* __restrict__ Wn1,
    const float* __restrict__ Wn2,
    const float* __restrict__ Wn3,
    const float* __restrict__ W_lin,
    const float* __restrict__ b_lin,
    float* __restrict__ ws,
    float* __restrict__ out)
{
    const int t = threadIdx.x;
    const int b = blockIdx.x;

    __shared__ __align__(16) float smem[4096];   // 16 KB

    float* EM  = ws + OFF_EM;
    float* ANF = ws + OFF_ANF;
    float* DEN = ws + OFF_DEN;
    float* EO  = ws + OFF_EO;
    float* G   = ws + OFF_G;
    float* AG  = ws + OFF_AG;
    unsigned* bar = reinterpret_cast<unsigned*>(ws + OFF_BAR);

    // De-poison barrier counter (0xAA poison -> 0). Idempotent; every block
    // tries at entry, ~20 us before any block can reach the first barrier.
    if (t == 0) atomicCAS(&bar[0], 0xAAAAAAAAu, 0u);
    // bar[1] (generation) works from any initial value.

    // ---------------- Phase A: edge_mean row b ------------------------------
    {
        const float4* efb = reinterpret_cast<const float4*>(edge_feat)
                          + (size_t)b * (NN * DD / 4) + t;
        float4 a0{0,0,0,0}, a1{0,0,0,0}, a2{0,0,0,0}, a3{0,0,0,0};
        float4 a4{0,0,0,0}, a5{0,0,0,0}, a6{0,0,0,0}, a7{0,0,0,0};
        #pragma unroll
        for (int m = 0; m < 8; ++m) {
            float4 v0 = efb[(8*m + 0) * 256];
            float4 v1 = efb[(8*m + 1) * 256];
            float4 v2 = efb[(8*m + 2) * 256];
            float4 v3 = efb[(8*m + 3) * 256];
            float4 v4 = efb[(8*m + 4) * 256];
            float4 v5 = efb[(8*m + 5) * 256];
            float4 v6 = efb[(8*m + 6) * 256];
            float4 v7 = efb[(8*m + 7) * 256];
            f4acc(a0, v0); f4acc(a1, v1); f4acc(a2, v2); f4acc(a3, v3);
            f4acc(a4, v4); f4acc(a5, v5); f4acc(a6, v6); f4acc(a7, v7);
        }
        f4acc(a0, a1); f4acc(a2, a3); f4acc(a4, a5); f4acc(a6, a7);
        f4acc(a0, a2); f4acc(a4, a6); f4acc(a0, a4);
        float4* red = reinterpret_cast<float4*>(smem);
        red[t] = a0;
        __syncthreads();
        if (t < 128) f4acc(red[t], red[t + 128]);
        __syncthreads();
        if (t < 64)  f4acc(red[t], red[t + 64]);
        __syncthreads();
        if (t < 32) {
            float4 m = red[t];
            f4acc(m, red[t + 32]);
            const float inv = 1.0f / (float)NN;
            m.x *= inv; m.y *= inv; m.z *= inv; m.w *= inv;
            reinterpret_cast<float4*>(EM + (size_t)b * DD)[t] = m;
        }
        __syncthreads();
    }

    // ---------------- Phase B: Anf + deg (this block's head/rows) -----------
    const int h  = b >> 7;
    const int r0 = (b & 127) * 4;
    float* ArowS = smem + 1408;   // [4][512] floats, kept live through layers

    {
        float4* As4 = reinterpret_cast<float4*>(ArowS);
        const float4* Ad4 = reinterpret_cast<const float4*>(
            adj + ((size_t)h * NN + r0) * NN);
        As4[t]       = Ad4[t];
        As4[t + 256] = Ad4[t + 256];
        __syncthreads();

        {   // deg -> denom: row rl = t>>6, 64-lane shuffle reduce
            const int rl = t >> 6, ln = t & 63;
            float s = 0.f;
            #pragma unroll
            for (int j = 0; j < 8; ++j) s += ArowS[rl * NN + ln + j * 64];
            #pragma unroll
            for (int m2 = 32; m2 >= 1; m2 >>= 1) s += __shfl_xor(s, m2);
            if (ln == 0)
                DEN[(size_t)h * NN + r0 + rl] = s + (s == 0.f ? 1.f : 0.f);
        }
        {   // Anf rows r0+rg, r0+rg+2 (rg = t>>7), col c2 = t&127
            const int c2 = t & 127, rg = t >> 7;
            float a0 = 0.f, a1 = 0.f;
            #pragma unroll 4
            for (int j = 0; j < NN; ++j) {
                float nf = node_feat[(size_t)j * DD + c2];
                a0 += ArowS[(rg + 0) * NN + j] * nf;
                a1 += ArowS[(rg + 2) * NN + j] * nf;
            }
            float* ab = ANF + ((size_t)h * NN + r0) * DD + c2;
            ab[(rg + 0) * DD] = a0;
            ab[(rg + 2) * DD] = a1;
        }
    }

    gbar(&bar[0], &bar[1]);

    // ---------------- Phases C..F ------------------------------------------
    const int c  = t & 31;
    const int ks = (t >> 5) & 1;   // k/j half split
    const int rr = t >> 6;         // row 0..3
    const int r  = r0 + rr;

    float* emS  = smem;            // [4][128]
    float* anfS = smem + 512;      // [4][128]
    float* aglS = smem + 1024;     // [4][32]
    float* pred = smem + 1152;     // [256]

    emS[t]        = EM[((size_t)r0 + (t >> 7)) * DD + (t & 127)];
    emS[t + 256]  = EM[((size_t)r0 + 2 + (t >> 7)) * DD + (t & 127)];
    anfS[t]       = ANF[((size_t)h * NN + r0 + (t >> 7)) * DD + (t & 127)];
    anfS[t + 256] = ANF[((size_t)h * NN + r0 + 2 + (t >> 7)) * DD + (t & 127)];
    __syncthreads();

    // Phase C: eo panels l=0..3 (keep l=0 in reg, store l>=1) + g0
    float eo0 = 0.f;
    #pragma unroll
    for (int l = 0; l < 4; ++l) {
        const float* We = W_edge + ((size_t)(h * LL + l) * DD) * GHD;
        float p = 0.f;
        #pragma unroll 8
        for (int k = ks * 64; k < ks * 64 + 64; ++k)
            p += emS[rr * DD + k] * We[(size_t)k * GHD + c];
        pred[t] = p;
        __syncthreads();
        if (ks == 0) {
            float v = pred[t] + pred[t + 32];
            if (l == 0) eo0 = v;
            else EO[((size_t)(h * LL + l) * NN + r) * GHD + c] = v;
        }
        __syncthreads();
    }
    {   // g0
        const float* W0 = Wn0 + (size_t)h * DD * GHD;
        float p = 0.f;
        #pragma unroll 8
        for (int k = ks * 64; k < ks * 64 + 64; ++k)
            p += anfS[rr * DD + k] * W0[(size_t)k * GHD + c];
        pred[t] = p;
        __syncthreads();
        if (ks == 0) {
            float v = pred[t] + pred[t + 32] + eo0;
            v /= DEN[(size_t)h * NN + r];
            v = v > 0.f ? v : 0.f;
            G[((size_t)(h * LL + 0) * NN + r) * GHD + c] = v;
        }
    }

    // Phases D/E/F: layers 1..3 (A rows still live in ArowS from phase B)
    #pragma unroll
    for (int l = 1; l < 4; ++l) {
        gbar(&bar[0], &bar[1]);
        {   // Ag_{l-1}[r][c], j-half per ks
            const float* gp = G + ((size_t)(h * LL + l - 1) * NN) * GHD;
            const float4* Ar4 = reinterpret_cast<const float4*>(ArowS);
            float s = 0.f;
            #pragma unroll 4
            for (int j4 = ks * 64; j4 < ks * 64 + 64; ++j4) {
                float4 a = Ar4[rr * 128 + j4];
                const float* gj = gp + (size_t)j4 * 4 * GHD + c;
                s += a.x * gj[0] + a.y * gj[GHD]
                   + a.z * gj[2 * GHD] + a.w * gj[3 * GHD];
            }
            pred[t] = s;
            __syncthreads();
            if (ks == 0) {
                float ag = pred[t] + pred[t + 32];
                AG[((size_t)(h * 3 + l - 1) * NN + r) * GHD + c] = ag;
                aglS[rr * GHD + c] = ag;
            }
            __syncthreads();
        }
        const float* Wnb = (l == 1) ? Wn1 : (l == 2) ? Wn2 : Wn3;
        const float* Wnl = Wnb + (size_t)h * (DD + GHD * l) * GHD;
        float p = 0.f;
        #pragma unroll 8
        for (int k = ks * 64; k < ks * 64 + 64; ++k)
            p += anfS[rr * DD + k] * Wnl[(size_t)k * GHD + c];
        #pragma unroll
        for (int kk = 0; kk < l; ++kk) {
            if ((kk & 1) == ks) {
                const float* agv = (kk == l - 1)
                    ? (aglS + rr * GHD)
                    : (AG + ((size_t)(h * 3 + kk) * NN + r) * GHD);
                const float* w = Wnl + ((size_t)(DD + kk * GHD)) * GHD + c;
                #pragma unroll 8
                for (int m = 0; m < GHD; ++m)
                    p += agv[m] * w[(size_t)m * GHD];
            }
        }
        pred[t] = p;
        __syncthreads();
        if (ks == 0) {
            float v = pred[t] + pred[t + 32]
                    + EO[((size_t)(h * LL + l) * NN + r) * GHD + c];
            v /= DEN[(size_t)h * NN + r];
            v = v > 0.f ? v : 0.f;
            G[((size_t)(h * LL + l) * NN + r) * GHD + c] = v;
        }
    }

    gbar(&bar[0], &bar[1]);

    // ---------------- Phase G: final linear, node n = b ---------------------
    {
        const int n  = b;
        const int o  = t & 127;
        const int hs = t >> 7;   // heads hs, hs+2
        float p = 0.f;
        for (int hh = hs; hh < HH; hh += 2) {
            #pragma unroll
            for (int l2 = 0; l2 < LL; ++l2) {
                const float* gr  = G + ((size_t)(hh * LL + l2) * NN + n) * GHD;
                const float* nfr = node_feat + (size_t)n * DD + l2 * GHD;
                const float* w   = W_lin + (size_t)(hh * DD + l2 * GHD) * OUTD + o;
                #pragma unroll 8
                for (int cc = 0; cc < GHD; ++cc)
                    p += (gr[cc] + nfr[cc]) * w[(size_t)cc * OUTD];
            }
        }
        smem[t] = p;
        __syncthreads();
        if (hs == 0)
            out[(size_t)n * OUTD + o] = smem[o] + smem[o + 128] + b_lin[o];
    }
}

// ===========================================================================
extern "C" void kernel_launch(void* const* d_in, const int* in_sizes, int n_in,
                              void* d_out, int out_size, void* d_ws, size_t ws_size,
                              hipStream_t stream)
{
    const float* node_feat = (const float*)d_in[0];
    const float* edge_feat = (const float*)d_in[1];
    const float* adj       = (const float*)d_in[2];
    const float* W_edge    = (const float*)d_in[3];
    const float* Wn0       = (const float*)d_in[4];
    const float* Wn1       = (const float*)d_in[5];
    const float* Wn2       = (const float*)d_in[6];
    const float* Wn3       = (const float*)d_in[7];
    const float* W_lin     = (const float*)d_in[8];
    const float* b_lin     = (const float*)d_in[9];
    float* out = (float*)d_out;
    float* ws  = (float*)d_ws;

    hipLaunchKernelGGL(fused_kernel, dim3(NBLK), dim3(256), 0, stream,
                       node_feat, edge_feat, adj, W_edge,
                       Wn0, Wn1, Wn2, Wn3, W_lin, b_lin, ws, out);
}

// Round 6
// 314.430 us; speedup vs baseline: 2.3815x; 2.3815x over previous
//
#include <hip/hip_runtime.h>
#include <cstddef>

// Problem constants
#define NN 512
#define DD 128
#define HH 4
#define LL 4
#define GHD 32
#define OUTD 128

// ws layout (float offsets)
static constexpr size_t OFF_ANF = 0;                                   // [H][N][D]
static constexpr size_t OFF_DEN = OFF_ANF + (size_t)HH * NN * DD;      // [H][N]
static constexpr size_t OFF_EO  = OFF_DEN + (size_t)HH * NN;           // [H][L][N][GHD]
static constexpr size_t OFF_G   = OFF_EO  + (size_t)HH * LL * NN * GHD;// [H][L][N][GHD]
static constexpr size_t OFF_AG  = OFF_G   + (size_t)HH * LL * NN * GHD;// [H][3][N][GHD]

__device__ __forceinline__ void f4acc(float4& a, const float4& v) {
    a.x += v.x; a.y += v.y; a.z += v.z; a.w += v.w;
}

// ===========================================================================
// K1: one block per node-row r. Phase-skewed 256KB edge stream -> em row,
// then A-rows -> deg, Anf, EO (16 panels), g0. All row-local.
// ===========================================================================
__global__ __launch_bounds__(256, 2) void k1_prep(
    const float* __restrict__ node_feat,
    const float* __restrict__ edge_feat,
    const float* __restrict__ adj,
    const float* __restrict__ W_edge,
    const float* __restrict__ Wn0,
    float* __restrict__ ws)
{
    const int r = blockIdx.x;
    const int t = threadIdx.x;

    __shared__ __align__(16) float4 red4[256];        // 4 KB
    __shared__ float ArowS[4 * NN];                   // 8 KB
    __shared__ float emS[DD];
    __shared__ float anfS[4 * DD];                    // 2 KB
    __shared__ float eo0S[4 * GHD];
    __shared__ float denS[4];
    __shared__ float pred[256];

    float* ANF = ws + OFF_ANF;
    float* DEN = ws + OFF_DEN;
    float* EO  = ws + OFF_EO;
    float* G   = ws + OFF_G;

    // ---- Phase 1: stream 256 KB slab, phase-skewed chunk order ----
    {
        const float4* efb = reinterpret_cast<const float4*>(edge_feat)
                          + (size_t)r * (NN * DD / 4);
        const int m0 = r & 63;
        float4 acc[8];
        #pragma unroll
        for (int u = 0; u < 8; ++u) acc[u] = float4{0, 0, 0, 0};
        #pragma unroll
        for (int batch = 0; batch < 4; ++batch) {
            float4 v[16];
            #pragma unroll
            for (int u = 0; u < 16; ++u) {
                int mm = (m0 + batch * 16 + u) & 63;   // chunk id, wraps
                v[u] = efb[(size_t)mm * 256 + t];
            }
            #pragma unroll
            for (int u = 0; u < 16; ++u) f4acc(acc[u & 7], v[u]);
        }
        #pragma unroll
        for (int u = 1; u < 8; ++u) f4acc(acc[0], acc[u]);
        red4[t] = acc[0];
        __syncthreads();
        if (t < 128) f4acc(red4[t], red4[t + 128]);
        __syncthreads();
        if (t < 64)  f4acc(red4[t], red4[t + 64]);
        __syncthreads();
        if (t < 32) {
            float4 m = red4[t];
            f4acc(m, red4[t + 32]);
            const float inv = 1.0f / (float)NN;
            m.x *= inv; m.y *= inv; m.z *= inv; m.w *= inv;
            reinterpret_cast<float4*>(emS)[t] = m;
        }
    }

    // ---- Phase 2: stage A rows (4 heads x 512) ----
    {
        float4* As4 = reinterpret_cast<float4*>(ArowS);
        const float4* adj4 = reinterpret_cast<const float4*>(adj);
        #pragma unroll
        for (int u = 0; u < 2; ++u) {
            int idx = u * 256 + t;                 // 0..511
            int h = idx >> 7, j4 = idx & 127;
            As4[idx] = adj4[(size_t)h * (NN * NN / 4) + (size_t)r * (NN / 4) + j4];
        }
    }
    __syncthreads();

    // ---- Phase 3: deg -> denom (wave w sums head w's row) ----
    {
        const int w = t >> 6, ln = t & 63;
        float s = 0.f;
        #pragma unroll
        for (int j = 0; j < 8; ++j) s += ArowS[w * NN + ln + j * 64];
        #pragma unroll
        for (int m = 32; m >= 1; m >>= 1) s += __shfl_xor(s, m);
        if (ln == 0) {
            float d = s + (s == 0.f ? 1.f : 0.f);
            denS[w] = d;
            DEN[(size_t)w * NN + r] = d;
        }
    }

    // ---- Phase 4: Anf[h][r][c] (c = t&127; hp = t>>7 -> heads hp, hp+2) ----
    {
        const int c = t & 127, hp = t >> 7;
        float a0 = 0.f, a1 = 0.f;
        #pragma unroll 8
        for (int j = 0; j < NN; ++j) {
            float nf = node_feat[(size_t)j * DD + c];
            a0 += ArowS[hp * NN + j] * nf;
            a1 += ArowS[(hp + 2) * NN + j] * nf;
        }
        anfS[hp * DD + c]       = a0;
        anfS[(hp + 2) * DD + c] = a1;
        ANF[((size_t)hp * NN + r) * DD + c]       = a0;
        ANF[((size_t)(hp + 2) * NN + r) * DD + c] = a1;
    }

    // ---- Phase 5: EO panels (c = t&31; g = t>>5 -> hl = g, g+8) ----
    {
        const int c = t & 31, g = t >> 5;
        float e0 = 0.f, e1 = 0.f;
        #pragma unroll 8
        for (int k = 0; k < DD; ++k) {
            float e = emS[k];
            e0 += e * W_edge[((size_t)g * DD + k) * GHD + c];
            e1 += e * W_edge[((size_t)(g + 8) * DD + k) * GHD + c];
        }
        EO[((size_t)g * NN + r) * GHD + c]       = e0;
        EO[((size_t)(g + 8) * NN + r) * GHD + c] = e1;
        if ((g & 3) == 0)       eo0S[(g >> 2) * GHD + c]       = e0;
        if (((g + 8) & 3) == 0) eo0S[((g + 8) >> 2) * GHD + c] = e1;
    }
    __syncthreads();

    // ---- Phase 6: g0 (h = t>>6, kh = (t>>5)&1, c = t&31) ----
    {
        const int h = t >> 6, kh = (t >> 5) & 1, c = t & 31;
        const float* W0 = Wn0 + (size_t)h * DD * GHD;
        float p = 0.f;
        #pragma unroll 8
        for (int k = kh * 64; k < kh * 64 + 64; ++k)
            p += anfS[h * DD + k] * W0[(size_t)k * GHD + c];
        pred[t] = p;
        __syncthreads();
        if (kh == 0) {
            float v = p + pred[t + 32] + eo0S[h * GHD + c];
            v /= denS[h];
            v = v > 0.f ? v : 0.f;
            G[((size_t)(h * LL + 0) * NN + r) * GHD + c] = v;
        }
    }
}

// ===========================================================================
// K2/K3: layer L in {1,2}. 1024 blocks (h = b>>8, rows (b&255)*2..+1).
// (R3-verified structure.)
// ===========================================================================
template <int L>
__global__ __launch_bounds__(256) void layer_kernel(
    const float* __restrict__ adj,
    const float* __restrict__ Wn,
    float* __restrict__ ws)
{
    constexpr int KIN = DD + GHD * L;
    const int b   = blockIdx.x;
    const int h   = b >> 8;
    const int r0  = (b & 255) * 2;
    const int t   = threadIdx.x;
    const int rr  = t >> 7;
    const int sub = (t >> 5) & 3;
    const int c   = t & 31;
    const int r   = r0 + rr;

    const float* anf = ws + OFF_ANF;
    const float* den = ws + OFF_DEN;
    const float* eo  = ws + OFF_EO;
    float* G  = ws + OFF_G;
    float* AG = ws + OFF_AG;

    __shared__ float smem[256 + 64 + 256];
    float* agp = smem;
    float* agl = smem + 256;
    float* pp  = smem + 320;

    {
        const float4* A4 = reinterpret_cast<const float4*>(
            adj + ((size_t)h * NN + r) * NN);
        const float* gp = G + (((size_t)h * LL + (L - 1)) * NN) * GHD;
        float s = 0.f;
        #pragma unroll 8
        for (int j4 = sub * 32; j4 < sub * 32 + 32; ++j4) {
            float4 a = A4[j4];
            const float* gj = gp + (size_t)j4 * 4 * GHD + c;
            s += a.x * gj[0] + a.y * gj[GHD] + a.z * gj[2 * GHD] + a.w * gj[3 * GHD];
        }
        agp[t] = s;
    }
    __syncthreads();
    if (sub == 0) {
        float ag = agp[rr * 128 + c] + agp[rr * 128 + 32 + c]
                 + agp[rr * 128 + 64 + c] + agp[rr * 128 + 96 + c];
        AG[(((size_t)h * 3 + (L - 1)) * NN + r) * GHD + c] = ag;
        agl[rr * GHD + c] = ag;
    }
    __syncthreads();

    float p = 0.f;
    {
        const float* Wnl = Wn + (size_t)h * KIN * GHD;
        const float* ar  = anf + ((size_t)h * NN + r) * DD;
        #pragma unroll 8
        for (int k = sub * 32; k < sub * 32 + 32; ++k)
            p += ar[k] * Wnl[(size_t)k * GHD + c];
        if (sub < L) {
            const float* agv = (sub == L - 1)
                ? (agl + rr * GHD)
                : (AG + (((size_t)h * 3 + sub) * NN + r) * GHD);
            const float* w = Wnl + (size_t)(DD + sub * GHD) * GHD + c;
            #pragma unroll 8
            for (int m = 0; m < GHD; ++m)
                p += agv[m] * w[(size_t)m * GHD];
        }
    }
    pp[t] = p;
    __syncthreads();
    if (sub == 0) {
        float tot = pp[rr * 128 + c] + pp[rr * 128 + 32 + c]
                  + pp[rr * 128 + 64 + c] + pp[rr * 128 + 96 + c]
                  + eo[(((size_t)h * LL + L) * NN + r) * GHD + c];
        float dn = den[(size_t)h * NN + r];
        float gv = tot / dn;
        gv = gv > 0.f ? gv : 0.f;
        G[(((size_t)h * LL + L) * NN + r) * GHD + c] = gv;
    }
}

// ===========================================================================
// K4: layer 3 + final linear. One block per node-row r; all 4 heads in-block.
// ===========================================================================
__global__ __launch_bounds__(256) void k4_last(
    const float* __restrict__ node_feat,
    const float* __restrict__ adj,
    const float* __restrict__ Wn3,     // [H][224][GHD]
    const float* __restrict__ W_lin,   // [512][128]
    const float* __restrict__ b_lin,
    const float* __restrict__ ws,
    float* __restrict__ out)
{
    const int r = blockIdx.x;
    const int t = threadIdx.x;

    __shared__ float ArowS[4 * NN];    // 8 KB
    __shared__ float anfS[4 * DD];     // 2 KB
    __shared__ float nfS[DD];
    __shared__ float ag2S[4 * GHD];
    __shared__ float g3S[4 * GHD];
    __shared__ float denS[4];
    __shared__ float Xs[4 * DD];       // concat(g_l)+nf per head
    __shared__ float pred[256];

    const float* ANF = ws + OFF_ANF;
    const float* DEN = ws + OFF_DEN;
    const float* EO  = ws + OFF_EO;
    const float* G   = ws + OFF_G;
    const float* AG  = ws + OFF_AG;

    // stage A rows, anf rows, nf row, den
    {
        float4* As4 = reinterpret_cast<float4*>(ArowS);
        const float4* adj4 = reinterpret_cast<const float4*>(adj);
        #pragma unroll
        for (int u = 0; u < 2; ++u) {
            int idx = u * 256 + t;
            int h = idx >> 7, j4 = idx & 127;
            As4[idx] = adj4[(size_t)h * (NN * NN / 4) + (size_t)r * (NN / 4) + j4];
        }
        #pragma unroll
        for (int u = 0; u < 2; ++u) {
            int idx = u * 256 + t;
            int h = idx >> 7, k = idx & 127;
            anfS[idx] = ANF[((size_t)h * NN + r) * DD + k];
        }
        if (t < DD) nfS[t] = node_feat[(size_t)r * DD + t];
        if (t < 4)  denS[t] = DEN[(size_t)t * NN + r];
    }
    __syncthreads();

    // Ag2[h][c]: h = t>>6, jh = (t>>5)&1, c = t&31
    {
        const int h = t >> 6, jh = (t >> 5) & 1, c = t & 31;
        const float* g2 = G + ((size_t)(h * LL + 2) * NN) * GHD;
        float s = 0.f;
        #pragma unroll 8
        for (int j = jh * 256; j < jh * 256 + 256; ++j)
            s += ArowS[h * NN + j] * g2[(size_t)j * GHD + c];
        pred[t] = s;
        __syncthreads();
        if (jh == 0) ag2S[h * GHD + c] = s + pred[t + 32];
        __syncthreads();
    }

    // g3[h][c]: h = t>>6, kh = (t>>5)&1, c = t&31
    {
        const int h = t >> 6, kh = (t >> 5) & 1, c = t & 31;
        const float* W3 = Wn3 + (size_t)h * 224 * GHD;
        float p = 0.f;
        #pragma unroll 8
        for (int k = kh * 64; k < kh * 64 + 64; ++k)
            p += anfS[h * DD + k] * W3[(size_t)k * GHD + c];
        if (kh == 0) {
            const float* ag0 = AG + ((size_t)(h * 3 + 0) * NN + r) * GHD;
            const float* w   = W3 + (size_t)DD * GHD + c;
            #pragma unroll 8
            for (int m = 0; m < GHD; ++m)
                p += ag0[m] * w[(size_t)m * GHD];
            const float* w2 = W3 + (size_t)(DD + 2 * GHD) * GHD + c;
            #pragma unroll 8
            for (int m = 0; m < GHD; ++m)
                p += ag2S[h * GHD + m] * w2[(size_t)m * GHD];
        } else {
            const float* ag1 = AG + ((size_t)(h * 3 + 1) * NN + r) * GHD;
            const float* w   = W3 + (size_t)(DD + GHD) * GHD + c;
            #pragma unroll 8
            for (int m = 0; m < GHD; ++m)
                p += ag1[m] * w[(size_t)m * GHD];
        }
        pred[t] = p;
        __syncthreads();
        if (kh == 0) {
            float v = p + pred[t + 32]
                    + EO[((size_t)(h * LL + 3) * NN + r) * GHD + c];
            v /= denS[h];
            v = v > 0.f ? v : 0.f;
            g3S[h * GHD + c] = v;
        }
        __syncthreads();
    }

    // X[h][k] = g_{k/32}[h][r][k%32] + nf[k]
    {
        #pragma unroll
        for (int u = 0; u < 2; ++u) {
            int idx = u * 256 + t;
            int h = idx >> 7, k = idx & 127;
            int l = k >> 5, cc = k & 31;
            float gv = (l < 3)
                ? G[((size_t)(h * LL + l) * NN + r) * GHD + cc]
                : g3S[h * GHD + cc];
            Xs[idx] = gv + nfS[k];
        }
    }
    __syncthreads();

    // out[r][o]: o = t&127, hs = t>>7 sums heads hs, hs+2
    {
        const int o = t & 127, hs = t >> 7;
        float p = 0.f;
        #pragma unroll
        for (int hh = hs; hh < HH; hh += 2) {
            const float* w = W_lin + (size_t)hh * DD * OUTD + o;
            #pragma unroll 8
            for (int k = 0; k < DD; ++k)
                p += Xs[hh * DD + k] * w[(size_t)k * OUTD];
        }
        pred[t] = p;
        __syncthreads();
        if (hs == 0)
            out[(size_t)r * OUTD + o] = p + pred[t + 128] + b_lin[o];
    }
}

// ===========================================================================
extern "C" void kernel_launch(void* const* d_in, const int* in_sizes, int n_in,
                              void* d_out, int out_size, void* d_ws, size_t ws_size,
                              hipStream_t stream)
{
    const float* node_feat = (const float*)d_in[0];
    const float* edge_feat = (const float*)d_in[1];
    const float* adj       = (const float*)d_in[2];
    const float* W_edge    = (const float*)d_in[3];
    const float* Wn0       = (const float*)d_in[4];
    const float* Wn1       = (const float*)d_in[5];
    const float* Wn2       = (const float*)d_in[6];
    const float* Wn3       = (const float*)d_in[7];
    const float* W_lin     = (const float*)d_in[8];
    const float* b_lin     = (const float*)d_in[9];
    float* out = (float*)d_out;
    float* ws  = (float*)d_ws;

    hipLaunchKernelGGL(k1_prep, dim3(NN), dim3(256), 0, stream,
                       node_feat, edge_feat, adj, W_edge, Wn0, ws);
    hipLaunchKernelGGL(layer_kernel<1>, dim3(1024), dim3(256), 0, stream, adj, Wn1, ws);
    hipLaunchKernelGGL(layer_kernel<2>, dim3(1024), dim3(256), 0, stream, adj, Wn2, ws);
    hipLaunchKernelGGL(k4_last, dim3(NN), dim3(256), 0, stream,
                       node_feat, adj, Wn3, W_lin, b_lin, ws, out);
}